// Round 1
// baseline (3363.908 us; speedup 1.0000x reference)
//
#include <hip/hip_runtime.h>

#define BB 4
#define CC 64
#define NNN 4096
#define OO 64
#define KK 20
#define CT 32
#define EPSF 1e-5f

// ---------------- K1: xx[n] = sum_c x[c][n]^2 in f64 ----------------
__global__ __launch_bounds__(256) void xx_kernel(const float* __restrict__ x, double* __restrict__ xx) {
    int g = blockIdx.x * 256 + threadIdx.x;          // 0..B*N-1
    int b = g >> 12, n = g & (NNN - 1);
    const float* xp = x + (size_t)b * CC * NNN + n;
    double s = 0.0;
    for (int c = 0; c < CC; ++c) {
        double v = (double)xp[(size_t)c * NNN];
        s += v * v;
    }
    xx[g] = s;
}

// ---------------- K2: per-point projections A = x*w1a^T, Bv = x*(w1b-w1a)^T ----------------
__global__ __launch_bounds__(256) void proj_kernel(const float* __restrict__ x, const float* __restrict__ w1,
                                                   float* __restrict__ A, float* __restrict__ Bv) {
    __shared__ float xs[CC][64];       // [c][p]
    __shared__ float ws1[OO][129];     // padded: 2-way max on reads
    int tid = threadIdx.x;
    int b = blockIdx.x >> 6;
    int p0 = (blockIdx.x & 63) << 6;
    const float* xb = x + (size_t)b * CC * NNN;
    for (int i = tid; i < CC * 16; i += 256) {
        int c = i >> 4, q = i & 15;
        *(float4*)&xs[c][q * 4] = *(const float4*)(xb + (size_t)c * NNN + p0 + q * 4);
    }
    for (int i = tid; i < OO * 32; i += 256) {
        int o = i >> 5, q = i & 31;
        float4 v = *(const float4*)(w1 + o * 128 + q * 4);
        ws1[o][q * 4 + 0] = v.x; ws1[o][q * 4 + 1] = v.y;
        ws1[o][q * 4 + 2] = v.z; ws1[o][q * 4 + 3] = v.w;
    }
    __syncthreads();
    int ti = tid >> 4, tj = tid & 15;
    float aA[4][4] = {{0.f}}, aD[4][4] = {{0.f}};
    for (int c = 0; c < CC; ++c) {
        float4 xv4 = *(const float4*)&xs[c][ti * 4];
        float xv[4] = {xv4.x, xv4.y, xv4.z, xv4.w};
        #pragma unroll
        for (int oo = 0; oo < 4; ++oo) {
            float wa = ws1[tj * 4 + oo][c];
            float wd = ws1[tj * 4 + oo][64 + c] - wa;
            #pragma unroll
            for (int pp = 0; pp < 4; ++pp) {
                aA[pp][oo] = fmaf(xv[pp], wa, aA[pp][oo]);
                aD[pp][oo] = fmaf(xv[pp], wd, aD[pp][oo]);
            }
        }
    }
    size_t base = ((size_t)b * NNN + p0) * 64;
    #pragma unroll
    for (int pp = 0; pp < 4; ++pp) {
        int p = ti * 4 + pp;
        *(float4*)(A  + base + (size_t)p * 64 + tj * 4) = make_float4(aA[pp][0], aA[pp][1], aA[pp][2], aA[pp][3]);
        *(float4*)(Bv + base + (size_t)p * 64 + tj * 4) = make_float4(aD[pp][0], aD[pp][1], aD[pp][2], aD[pp][3]);
    }
}

// ---------------- K3: fused f64 distances + top-20 per row ----------------
// block = 256 thr, handles 64 rows x all 4096 candidates of one batch.
__global__ __launch_bounds__(256) void knn_kernel(const float* __restrict__ x, const double* __restrict__ xx,
                                                  int* __restrict__ idxOut) {
    __shared__ float rowT[CC][64];          // 16 KB
    __shared__ float candT[CC][CT];         // 8 KB
    __shared__ double distT[64][CT + 1];    // 16.9 KB, pad -> conflict-light
    __shared__ double xxr[64];
    __shared__ double xxc[CT];
    __shared__ double listD[64][KK];        // 10.2 KB
    __shared__ int listI[64][KK];           // 5.1 KB
    int tid = threadIdx.x;
    int b = blockIdx.x >> 6;
    int r0 = (blockIdx.x & 63) << 6;
    const float* xb = x + (size_t)b * CC * NNN;
    for (int i = tid; i < CC * 16; i += 256) {
        int c = i >> 4, q = i & 15;
        *(float4*)&rowT[c][q * 4] = *(const float4*)(xb + (size_t)c * NNN + r0 + q * 4);
    }
    if (tid < 64) {
        xxr[tid] = xx[b * NNN + r0 + tid];
        for (int q = 0; q < KK; ++q) { listD[tid][q] = -1.0e300; listI[tid][q] = 0x7fffffff; }
    }
    __syncthreads();
    int ti = tid >> 4, tj = tid & 15;           // rows ti*4..+3, cands tj*2..+1
    double mv = -1.0e300; int mp = 0, mIdx = 0x7fffffff;   // worst entry of row `tid` (tid<64)
    for (int j0 = 0; j0 < NNN; j0 += CT) {
        for (int i = tid; i < CC * (CT / 4); i += 256) {
            int c = i >> 3, q = i & 7;
            *(float4*)&candT[c][q * 4] = *(const float4*)(xb + (size_t)c * NNN + j0 + q * 4);
        }
        if (tid < CT) xxc[tid] = xx[b * NNN + j0 + tid];
        __syncthreads();
        // compute: exact fp32->f64 products, f64 accumulate (matches np float64 ref)
        double acc[4][2] = {};
        for (int c = 0; c < CC; ++c) {
            float4 rv4 = *(const float4*)&rowT[c][ti * 4];
            float2 cv2 = *(const float2*)&candT[c][tj * 2];
            double r[4] = {(double)rv4.x, (double)rv4.y, (double)rv4.z, (double)rv4.w};
            double cd[2] = {(double)cv2.x, (double)cv2.y};
            #pragma unroll
            for (int pp = 0; pp < 4; ++pp)
                #pragma unroll
                for (int qq = 0; qq < 2; ++qq)
                    acc[pp][qq] = fma(r[pp], cd[qq], acc[pp][qq]);
        }
        #pragma unroll
        for (int pp = 0; pp < 4; ++pp)
            #pragma unroll
            for (int qq = 0; qq < 2; ++qq)
                distT[ti * 4 + pp][tj * 2 + qq] =
                    2.0 * acc[pp][qq] - xxr[ti * 4 + pp] - xxc[tj * 2 + qq];
        __syncthreads();
        // top-k merge: one lane per row; insertions get rare fast (~106 total per row)
        if (tid < 64) {
            for (int j = 0; j < CT; ++j) {
                double d = distT[tid][j];
                int jg = j0 + j;
                if (d > mv || (d == mv && jg < mIdx)) {
                    listD[tid][mp] = d; listI[tid][mp] = jg;
                    mv = listD[tid][0]; mIdx = listI[tid][0]; mp = 0;
                    for (int q = 1; q < KK; ++q) {
                        double dq = listD[tid][q]; int iq = listI[tid][q];
                        if (dq < mv || (dq == mv && iq > mIdx)) { mv = dq; mIdx = iq; mp = q; }
                    }
                }
            }
        }
        // no barrier needed here: next compute's distT writes are fenced by the
        // post-staging __syncthreads above; staging doesn't touch distT/lists.
    }
    if (tid < 64) {
        for (int q = 0; q < KK; ++q)
            idxOut[((size_t)b * NNN + r0 + tid) * KK + q] = listI[tid][q];
    }
}

// ---------------- K4: h1 = relu(bn1(A[nb]+Bv[n])); h2 = relu(bn2(h1·w2^T)); max over k ----------------
// block = 256 (4 waves), 32 points/block; lane = output channel o2; w2 row held in VGPRs.
__global__ __launch_bounds__(256) void edge_kernel(const float* __restrict__ A, const float* __restrict__ Bv,
        const int* __restrict__ idx, const float* __restrict__ w2,
        const float* __restrict__ g1, const float* __restrict__ be1, const float* __restrict__ m1, const float* __restrict__ v1,
        const float* __restrict__ g2, const float* __restrict__ be2, const float* __restrict__ m2, const float* __restrict__ v2,
        float* __restrict__ out) {
    __shared__ float h1buf[4][KK][64];     // per-wave staging, 20 KB
    __shared__ float resT[64][33];         // padded transpose buffer
    int tid = threadIdx.x;
    int lane = tid & 63, w = tid >> 6;
    int b = blockIdx.x >> 7;
    int n0 = (blockIdx.x & 127) * 32;
    float s1 = g1[lane] * rsqrtf(v1[lane] + EPSF);
    float bb1 = be1[lane] - m1[lane] * s1;
    float s2 = g2[lane] * rsqrtf(v2[lane] + EPSF);
    float bb2 = be2[lane] - m2[lane] * s2;
    float w2r[64];
    #pragma unroll
    for (int o = 0; o < 64; ++o) w2r[o] = w2[lane * 64 + o];   // row o2 of w2, once per block
    for (int p = 0; p < 8; ++p) {
        int n = n0 + w * 8 + p;
        size_t pb = (size_t)b * NNN + n;
        float bv = Bv[pb * 64 + lane];
        const int* ip = idx + pb * KK;
        #pragma unroll
        for (int k = 0; k < KK; ++k) {
            int nb = ip[k];                                    // uniform -> scalar load
            float av = A[((size_t)b * NNN + nb) * 64 + lane];  // coalesced 256B gather (L2-resident)
            h1buf[w][k][lane] = fmaxf(0.f, fmaf(av + bv, s1, bb1));
        }
        __syncthreads();
        float mx = -1e30f;
        for (int k = 0; k < KK; ++k) {
            const float4* hb = (const float4*)&h1buf[w][k][0];
            float dot = 0.f;
            #pragma unroll
            for (int o4 = 0; o4 < 16; ++o4) {
                float4 h = hb[o4];                             // uniform addr -> broadcast read
                dot = fmaf(w2r[o4 * 4 + 0], h.x, dot);
                dot = fmaf(w2r[o4 * 4 + 1], h.y, dot);
                dot = fmaf(w2r[o4 * 4 + 2], h.z, dot);
                dot = fmaf(w2r[o4 * 4 + 3], h.w, dot);
            }
            mx = fmaxf(mx, fmaxf(0.f, fmaf(dot, s2, bb2)));
        }
        resT[lane][w * 8 + p] = mx;
        __syncthreads();
    }
    for (int i = tid; i < 64 * 32; i += 256) {
        int o2 = i >> 5, pp = i & 31;
        out[((size_t)b * 64 + o2) * NNN + n0 + pp] = resT[o2][pp];
    }
}

extern "C" void kernel_launch(void* const* d_in, const int* in_sizes, int n_in,
                              void* d_out, int out_size, void* d_ws, size_t ws_size,
                              hipStream_t stream) {
    const float* x   = (const float*)d_in[0];
    const float* w1  = (const float*)d_in[1];
    const float* g1  = (const float*)d_in[2];
    const float* be1 = (const float*)d_in[3];
    const float* m1  = (const float*)d_in[4];
    const float* v1  = (const float*)d_in[5];
    const float* w2  = (const float*)d_in[6];
    const float* g2  = (const float*)d_in[7];
    const float* be2 = (const float*)d_in[8];
    const float* m2  = (const float*)d_in[9];
    const float* v2  = (const float*)d_in[10];
    // ws layout: xx f64 (128KB) | A f32 (4MB) | Bv f32 (4MB) | idx i32 (1.25MB) = 9.4MB
    char* ws = (char*)d_ws;
    double* xx = (double*)ws;
    float*  A  = (float*)(ws + 131072);
    float*  Bv = (float*)(ws + 131072 + 4194304);
    int*    nidx = (int*)(ws + 131072 + 2 * 4194304);
    float*  out = (float*)d_out;

    hipLaunchKernelGGL(xx_kernel,   dim3(BB * NNN / 256), dim3(256), 0, stream, x, xx);
    hipLaunchKernelGGL(proj_kernel, dim3(BB * (NNN / 64)), dim3(256), 0, stream, x, w1, A, Bv);
    hipLaunchKernelGGL(knn_kernel,  dim3(BB * (NNN / 64)), dim3(256), 0, stream, x, xx, nidx);
    hipLaunchKernelGGL(edge_kernel, dim3(BB * (NNN / 32)), dim3(256), 0, stream,
                       A, Bv, nidx, w2, g1, be1, m1, v1, g2, be2, m2, v2, out);
}